// Round 8
// baseline (347.845 us; speedup 1.0000x reference)
//
#include <hip/hip_runtime.h>
#include <hip/hip_bf16.h>
#include <math.h>

// ---------------- types ----------------
typedef __attribute__((ext_vector_type(4))) float   f32x4;
typedef __attribute__((ext_vector_type(8))) short   short8;
typedef __attribute__((ext_vector_type(8))) __bf16  bf16x8;

union SB8 { short8 s; bf16x8 b; };

__device__ __forceinline__ short f2bf(float f) {
  union { float f; unsigned u; } v; v.f = f;
  unsigned r = v.u + 0x7fffu + ((v.u >> 16) & 1u);   // RNE
  return (short)(r >> 16);
}

__device__ __forceinline__ short8 cvt8(f32x4 a, f32x4 b) {
  short8 r;
  r[0] = f2bf(a[0]); r[1] = f2bf(a[1]); r[2] = f2bf(a[2]); r[3] = f2bf(a[3]);
  r[4] = f2bf(b[0]); r[5] = f2bf(b[1]); r[6] = f2bf(b[2]); r[7] = f2bf(b[3]);
  return r;
}

// async global->LDS, 16B per lane; dest is wave-uniform base + lane*16
__device__ __forceinline__ void ldsload16(const short* g, short* l) {
  __builtin_amdgcn_global_load_lds(
      (const __attribute__((address_space(1))) unsigned int*)g,
      (__attribute__((address_space(3))) unsigned int*)l, 16, 0, 0);
}

// Problem constants
#define TT   2048
#define DD   1024        // K of gemm1, N of gemm2
#define HH   704
#define HSS  1408
#define EE   16
#define CAP  2048
#define CSTR 32          // counts stride in ints (128B apart)
#define XSZ  2097152ULL  // x elems
#define GATE_BLOCKS 512
#define XCVT_BLOCKS 256  // XSZ / 8192

// ---------------- fused gate + x fp32->bf16 convert ----------------
// Weights are NO LONGER pre-converted: the GEMMs reg-stage fp32->bf16 during
// LDS staging (kills the 170MB serialized convert pass, r6 pivot).
__global__ __launch_bounds__(256)
void gate_cvt(const float* __restrict__ x, short* __restrict__ xb,
              const float* __restrict__ gw, const float* __restrict__ gb,
              int* __restrict__ counts, int* __restrict__ tok,
              float* __restrict__ wgt, int* __restrict__ eslot)
{
  if (blockIdx.x >= GATE_BLOCKS) {
    const int tid = threadIdx.x;
    const size_t base = (size_t)(blockIdx.x - GATE_BLOCKS) * 8192;
    f32x4 va[8];
    #pragma unroll
    for (int k = 0; k < 4; k++) {
      va[2 * k]     = *(const f32x4*)(x + base + (size_t)k * 2048 + tid * 8);
      va[2 * k + 1] = *(const f32x4*)(x + base + (size_t)k * 2048 + tid * 8 + 4);
    }
    #pragma unroll
    for (int k = 0; k < 4; k++)
      *(short8*)(xb + base + (size_t)k * 2048 + tid * 8) = cvt8(va[2 * k], va[2 * k + 1]);
    return;
  }

  // ---- gate part (unchanged) ----
  const int lane = threadIdx.x & 63;
  const int wid  = threadIdx.x >> 6;
  const int t    = blockIdx.x * 4 + wid;
  const int e    = lane & 15;
  const int p    = lane >> 4;

  const float* xp = x + (size_t)t * DD + p * 256;
  const float* gp = gw + (size_t)e * DD + p * 256;

  double a0 = 0.0, a1 = 0.0, a2 = 0.0, a3 = 0.0;
  #pragma unroll 8
  for (int i = 0; i < 64; i++) {
    f32x4 xa = *(const f32x4*)(xp + i * 4);
    f32x4 ga = *(const f32x4*)(gp + i * 4);
    a0 += (double)xa[0] * (double)ga[0];
    a1 += (double)xa[1] * (double)ga[1];
    a2 += (double)xa[2] * (double)ga[2];
    a3 += (double)xa[3] * (double)ga[3];
  }
  double acc = (a0 + a1) + (a2 + a3);
  acc += __shfl_xor(acc, 16);
  acc += __shfl_xor(acc, 32);
  float accf = (float)acc;

  float lf[EE], sc[EE], r[EE];
  #pragma unroll
  for (int j = 0; j < EE; j++) lf[j] = __shfl(accf, j);
  #pragma unroll
  for (int j = 0; j < EE; j++) {
    sc[j] = 1.f / (1.f + expf(-lf[j]));
    r[j] = sc[j] + gb[j];
  }
  float gs[4];
  #pragma unroll
  for (int g = 0; g < 4; g++) {
    float m1 = -1e30f, m2 = -1e30f;
    #pragma unroll
    for (int j = 0; j < 4; j++) {
      float v = r[g * 4 + j];
      if (v > m1) { m2 = m1; m1 = v; }
      else if (v > m2) { m2 = v; }
    }
    gs[g] = m1 + m2;
  }
  int g1 = 0, g2 = -1; float b1 = -1e30f, b2 = -1e30f;
  #pragma unroll
  for (int g = 0; g < 4; g++) {
    if (gs[g] > b1) { b2 = b1; g2 = g1; b1 = gs[g]; g1 = g; }
    else if (gs[g] > b2) { b2 = gs[g]; g2 = g; }
  }
  int idx[4]; float wv[4]; float wsum = 0.f;
  unsigned used = 0;
  #pragma unroll
  for (int k = 0; k < 4; k++) {
    float best = -1e30f; int bi = 0;
    #pragma unroll
    for (int j = 0; j < EE; j++) {
      int g = j >> 2;
      bool keep = (g == g1) || (g == g2);
      if (keep && !((used >> j) & 1) && r[j] > best) { best = r[j]; bi = j; }
    }
    used |= 1u << bi; idx[k] = bi; wv[k] = sc[bi]; wsum += sc[bi];
  }
  float div = wsum < 1e-9f ? 1e-9f : wsum;
  if (lane < 4) {
    float w = wv[lane] / div * 2.5446f;
    int slot = atomicAdd(&counts[idx[lane] * CSTR], 1);
    tok[idx[lane] * CAP + slot] = t;
    wgt[idx[lane] * CAP + slot] = w;
    eslot[t * 4 + lane] = (idx[lane] << 16) | slot;
  }
}

// sync helpers. Raw s_barrier needs explicit lgkmcnt drain for ds_write
// cross-wave visibility; vmcnt(0) placed AFTER the MFMA body = full cover.
#define PIPE_VM_WAIT() do { \
    asm volatile("s_waitcnt vmcnt(0)" ::: "memory"); \
    __builtin_amdgcn_sched_barrier(0); \
    __builtin_amdgcn_s_barrier(); \
    __builtin_amdgcn_sched_barrier(0); } while (0)
#define PIPE_LGKM_BAR() do { \
    asm volatile("s_waitcnt lgkmcnt(0)" ::: "memory"); \
    __builtin_amdgcn_sched_barrier(0); \
    __builtin_amdgcn_s_barrier(); \
    __builtin_amdgcn_sched_barrier(0); } while (0)

// ---------------- merged GEMM1 + SwiGLU (fp32-B reg-staged, 8-wave dbuf) --------
// grid (11, 16, 18) = 3168, 512 threads. Tile M=128, N=64 dual, BK=64, 64KB LDS.
// A (gathered x rows, bf16) via global_load_lds; B (W1/W3) loaded fp32 ->
// cvt8 -> ds_write_b128 into the SAME swizzled slot gload_lds used.
// Per K-step: ISSUE(next: 2 A-gload_lds + 4 B-f32x4) -> MFMA(cur) ->
// vmcnt(0)+barrier -> WRITE(next B) -> lgkmcnt(0)+barrier.  Writes to buf c^1
// are two barriers after its last reader (race-checked).
// Expert-clustered XCD swizzle + Nt-minor (r1/r5, confirmed).
__global__ __launch_bounds__(512, 2)
void gemm1_merged(const short* __restrict__ xb,
                  const float* __restrict__ w1f, const float* __restrict__ w3f,
                  const float* __restrict__ ws1f, const float* __restrict__ ws3f,
                  short* __restrict__ act_r, short* __restrict__ act_s,
                  const int* __restrict__ counts, const int* __restrict__ tok)
{
  const int F = blockIdx.x + 11 * (blockIdx.y + 16 * blockIdx.z);
  const int r8 = F & 7, rank = F >> 3;          // 3168 = 8*396
  int z, Mt, Ntc;
  if (rank < 352) {                   // routed: expert z clustered on XCD z&7
    z = r8 + 8 * (rank / 176);
    const int p = rank % 176;
    Mt = p / 11; Ntc = p % 11;        // Nt-minor
  } else {                            // shared FFN, spread across XCDs
    z = 16;
    const int p = (rank - 352) * 8 + r8;
    Mt = p / 22; Ntc = p % 22;
  }

  const bool routed = (z < EE);
  int cnt, N, rowbase = 0;
  const float *W1, *W3;
  short* act;
  if (routed) {
    cnt = counts[z * CSTR];
    if (Mt * 128 >= cnt) return;
    int rb = 0;
    for (int i = 0; i < z; i++) rb += counts[i * CSTR];
    rowbase = rb;
    N = HH;
    W1 = w1f + (size_t)z * HH * DD;
    W3 = w3f + (size_t)z * HH * DD;
    act = act_r;
  } else {
    cnt = TT; N = HSS; W1 = ws1f; W3 = ws3f; act = act_s;
  }
  const int NtB = Ntc * 64;

  __shared__ __align__(16) short lA [2][128 * 64];
  __shared__ __align__(16) short lB1[2][64 * 64];
  __shared__ __align__(16) short lB3[2][64 * 64];

  const int tid = threadIdx.x, lane = tid & 63, wv = tid >> 6;   // wv 0..7
  const int srow = lane >> 3, schunk = lane & 7, scg = schunk ^ srow;

  const short* pa[2];
  #pragma unroll
  for (int i = 0; i < 2; i++) {
    const int g = wv * 2 + i;
    int arow = Mt * 128 + g * 8 + srow;
    if (routed) {
      int slot = arow < cnt ? arow : cnt - 1;
      arow = tok[z * CAP + slot];
    }
    pa[i] = xb + (size_t)arow * DD + scg * 8;
  }
  const float *pb1f, *pb3f;
  {
    const int brow = NtB + wv * 8 + srow;      // <= N-1 (exact tiling)
    pb1f = W1 + (size_t)brow * DD + scg * 8;
    pb3f = W3 + (size_t)brow * DD + scg * 8;
  }

  f32x4 acc1[4], acc3[4];
  #pragma unroll
  for (int i = 0; i < 4; i++) { acc1[i] = (f32x4)0.f; acc3[i] = (f32x4)0.f; }
  f32x4 rb1[2], rb3[2];

  const int q = lane >> 4, r7 = lane & 7, hi = (lane & 15) >> 3;
  const int wc = wv & 3, mh = wv >> 2;
  const int wofs = wv * 512 + srow * 64 + schunk * 8;  // B stage slot (elems)

#define STAGE1_ISSUE(c, kk) do { \
    ldsload16(pa[0] + (kk), &lA[c][(wv * 2 + 0) * 512]); \
    ldsload16(pa[1] + (kk), &lA[c][(wv * 2 + 1) * 512]); \
    rb1[0] = *(const f32x4*)(pb1f + (kk)); \
    rb1[1] = *(const f32x4*)(pb1f + (kk) + 4); \
    rb3[0] = *(const f32x4*)(pb3f + (kk)); \
    rb3[1] = *(const f32x4*)(pb3f + (kk) + 4); } while (0)

#define STAGE1_WRITE(c) do { \
    *(short8*)(&lB1[c][wofs]) = cvt8(rb1[0], rb1[1]); \
    *(short8*)(&lB3[c][wofs]) = cvt8(rb3[0], rb3[1]); } while (0)

#define GEMM1_BODY(c) do { \
    _Pragma("unroll") for (int kc = 0; kc < 2; kc++) { \
      const int cx = (kc * 4 + q) ^ r7; \
      SB8 b1f, b3f; \
      b1f.s = *(const short8*)(&lB1[c][((wc * 2 + hi) * 64 + r7 * 8 + cx) * 8]); \
      b3f.s = *(const short8*)(&lB3[c][((wc * 2 + hi) * 64 + r7 * 8 + cx) * 8]); \
      _Pragma("unroll") for (int mt = 0; mt < 4; mt++) { \
        SB8 af; af.s = *(const short8*)(&lA[c][((2 * (mh * 4 + mt) + hi) * 64 + r7 * 8 + cx) * 8]); \
        acc1[mt] = __builtin_amdgcn_mfma_f32_16x16x32_bf16(af.b, b1f.b, acc1[mt], 0, 0, 0); \
        acc3[mt] = __builtin_amdgcn_mfma_f32_16x16x32_bf16(af.b, b3f.b, acc3[mt], 0, 0, 0); \
      } } } while (0)

  // prologue
  STAGE1_ISSUE(0, 0);
  asm volatile("s_waitcnt vmcnt(0)" ::: "memory");
  __builtin_amdgcn_sched_barrier(0);
  STAGE1_WRITE(0);
  PIPE_LGKM_BAR();
  int cur = 0;
  for (int kk = 64; kk < DD; kk += 64) {
    STAGE1_ISSUE(cur ^ 1, kk);
    GEMM1_BODY(cur);
    PIPE_VM_WAIT();            // next A landed in LDS; next B in regs
    STAGE1_WRITE(cur ^ 1);
    PIPE_LGKM_BAR();           // next buffer fully visible
    cur ^= 1;
  }
  GEMM1_BODY(cur);

  const int quad = lane >> 4, lcol = lane & 15;
  const int col = NtB + wc * 16 + lcol;
  #pragma unroll
  for (int mt = 0; mt < 4; mt++) {
    #pragma unroll
    for (int rg = 0; rg < 4; rg++) {
      const int r = Mt * 128 + (mh * 4 + mt) * 16 + quad * 4 + rg;
      if (r < cnt) {
        float g = acc1[mt][rg], u = acc3[mt][rg];
        float a = g / (1.f + __expf(-g)) * u;
        act[(size_t)(rowbase + r) * N + col] = f2bf(a);
      }
    }
  }
#undef STAGE1_ISSUE
#undef STAGE1_WRITE
#undef GEMM1_BODY
}

// ---------------- merged GEMM2 (down proj, fp32-B reg-staged) ----------------
// grid (8, 16, 17) = 2176, 512 threads, tile 128x128, BK=64, dbuf 64KB LDS.
// A = act bf16 via gload_lds; B = w2/ws2 fp32 reg-staged (routed fp32 panel
// 2.9MB still L2-fits under the expert cluster swizzle).
__global__ __launch_bounds__(512, 2)
void gemm2_merged(const short* __restrict__ act_r, const short* __restrict__ act_s,
                  const float* __restrict__ w2f, const float* __restrict__ ws2f,
                  float* __restrict__ y, float* __restrict__ outr,
                  const int* __restrict__ counts, const float* __restrict__ wgt)
{
  const int F = blockIdx.x + 8 * (blockIdx.y + 16 * blockIdx.z);
  const int r8 = F & 7, rank = F >> 3;
  int z, Mt, Nt;
  if (rank < 256) {
    z = r8 + 8 * (rank >> 7);
    const int p = rank & 127;
    Mt = p >> 3; Nt = p & 7;
  } else {
    z = 16;
    const int p = (rank - 256) * 8 + r8;
    Mt = p >> 3; Nt = p & 7;
  }

  const bool routed = (z < EE);

  int cnt, Kd, rowbase = 0;
  const short* A;
  const float* W;
  if (routed) {
    cnt = counts[z * CSTR];
    if (Mt * 128 >= cnt) return;
    int rb = 0;
    for (int i = 0; i < z; i++) rb += counts[i * CSTR];
    rowbase = rb;
    Kd = HH;
    A = act_r + (size_t)rowbase * HH;
    W = w2f + (size_t)z * DD * HH;
  } else {
    cnt = TT; Kd = HSS; A = act_s; W = ws2f;
  }

  __shared__ __align__(16) short lA[2][128 * 64];
  __shared__ __align__(16) short lB[2][128 * 64];

  const int tid = threadIdx.x, lane = tid & 63, wv = tid >> 6;   // wv 0..7
  const int srow = lane >> 3, schunk = lane & 7, scg = schunk ^ srow;

  const short* pa[2]; const float* pbf[2];
  #pragma unroll
  for (int i = 0; i < 2; i++) {
    const int g = wv * 2 + i;
    int arow = Mt * 128 + g * 8 + srow;
    if (arow >= cnt) arow = cnt - 1;
    pa[i] = A + (size_t)arow * Kd + scg * 8;
    const int brow = Nt * 128 + g * 8 + srow;   // <= 1023 always
    pbf[i] = W + (size_t)brow * Kd + scg * 8;
  }

  f32x4 acc[4][2];
  #pragma unroll
  for (int i = 0; i < 4; i++) { acc[i][0] = (f32x4)0.f; acc[i][1] = (f32x4)0.f; }
  f32x4 rbw[4];

  const int q = lane >> 4, r7 = lane & 7, hi = (lane & 15) >> 3;
  const int wc = wv & 3, mh = wv >> 2;
  const int wofs0 = (wv * 2 + 0) * 512 + srow * 64 + schunk * 8;
  const int wofs1 = (wv * 2 + 1) * 512 + srow * 64 + schunk * 8;

#define STAGE2_ISSUE(c, kk) do { \
    ldsload16(pa[0] + (kk), &lA[c][(wv * 2 + 0) * 512]); \
    ldsload16(pa[1] + (kk), &lA[c][(wv * 2 + 1) * 512]); \
    rbw[0] = *(const f32x4*)(pbf[0] + (kk)); \
    rbw[1] = *(const f32x4*)(pbf[0] + (kk) + 4); \
    rbw[2] = *(const f32x4*)(pbf[1] + (kk)); \
    rbw[3] = *(const f32x4*)(pbf[1] + (kk) + 4); } while (0)

#define STAGE2_WRITE(c) do { \
    *(short8*)(&lB[c][wofs0]) = cvt8(rbw[0], rbw[1]); \
    *(short8*)(&lB[c][wofs1]) = cvt8(rbw[2], rbw[3]); } while (0)

#define GEMM2_BODY(c) do { \
    _Pragma("unroll") for (int kc = 0; kc < 2; kc++) { \
      const int cx = (kc * 4 + q) ^ r7; \
      SB8 bf[2]; \
      _Pragma("unroll") for (int ntl = 0; ntl < 2; ntl++) { \
        const int a16 = ((wc * 2 + ntl) * 2 + hi) * 64 + r7 * 8 + cx; \
        bf[ntl].s = *(const short8*)(&lB[c][a16 * 8]); \
      } \
      _Pragma("unroll") for (int mt = 0; mt < 4; mt++) { \
        const int a16 = (2 * (mh * 4 + mt) + hi) * 64 + r7 * 8 + cx; \
        SB8 af; af.s = *(const short8*)(&lA[c][a16 * 8]); \
        acc[mt][0] = __builtin_amdgcn_mfma_f32_16x16x32_bf16(af.b, bf[0].b, acc[mt][0], 0, 0, 0); \
        acc[mt][1] = __builtin_amdgcn_mfma_f32_16x16x32_bf16(af.b, bf[1].b, acc[mt][1], 0, 0, 0); \
      } } } while (0)

  STAGE2_ISSUE(0, 0);
  asm volatile("s_waitcnt vmcnt(0)" ::: "memory");
  __builtin_amdgcn_sched_barrier(0);
  STAGE2_WRITE(0);
  PIPE_LGKM_BAR();
  int cur = 0;
  for (int kk = 64; kk < Kd; kk += 64) {
    STAGE2_ISSUE(cur ^ 1, kk);
    GEMM2_BODY(cur);
    PIPE_VM_WAIT();
    STAGE2_WRITE(cur ^ 1);
    PIPE_LGKM_BAR();
    cur ^= 1;
  }
  GEMM2_BODY(cur);

  const int quad = lane >> 4, lcol = lane & 15;
  #pragma unroll
  for (int mt = 0; mt < 4; mt++) {
    #pragma unroll
    for (int ntl = 0; ntl < 2; ntl++) {
      const int col = Nt * 128 + (wc * 2 + ntl) * 16 + lcol;
      #pragma unroll
      for (int rg = 0; rg < 4; rg++) {
        const int slot = Mt * 128 + (mh * 4 + mt) * 16 + quad * 4 + rg;
        const float v = acc[mt][ntl][rg];
        if (routed) {
          if (slot < cnt) {
            const float w = wgt[z * CAP + slot];
            outr[(size_t)(rowbase + slot) * DD + col] = w * v;
          }
        } else {
          y[(size_t)slot * DD + col] = v;
        }
      }
    }
  }
#undef STAGE2_ISSUE
#undef STAGE2_WRITE
#undef GEMM2_BODY
}

// ---------------- combine: y[t] += sum_k outr[offs[e_k]+slot_k] ----------------
__global__ __launch_bounds__(256)
void combine_kernel(float* __restrict__ y, const float* __restrict__ outr,
                    const int* __restrict__ eslot, const int* __restrict__ counts)
{
  const int t = blockIdx.x;
  const int d = threadIdx.x * 4;

  int offs[EE];
  int s = 0;
  #pragma unroll
  for (int i = 0; i < EE; i++) { offs[i] = s; s += counts[i * CSTR]; }

  f32x4 accv = *(f32x4*)(y + (size_t)t * DD + d);
  #pragma unroll
  for (int k = 0; k < 4; k++) {
    const int es = eslot[t * 4 + k];
    const int row = offs[es >> 16] + (es & 0xFFFF);
    accv += *(const f32x4*)(outr + (size_t)row * DD + d);
  }
  *(f32x4*)(y + (size_t)t * DD + d) = accv;
}

// ---------------- launch ----------------
extern "C" void kernel_launch(void* const* d_in, const int* in_sizes, int n_in,
                              void* d_out, int out_size, void* d_ws, size_t ws_size,
                              hipStream_t stream) {
  const float* x      = (const float*)d_in[0];
  const float* gate_w = (const float*)d_in[1];
  const float* gate_b = (const float*)d_in[2];
  const float* w1     = (const float*)d_in[3];
  const float* w3     = (const float*)d_in[4];
  const float* w2     = (const float*)d_in[5];
  const float* ws1    = (const float*)d_in[6];
  const float* ws3    = (const float*)d_in[7];
  const float* ws2    = (const float*)d_in[8];
  float* y = (float*)d_out;

  char* ws = (char*)d_ws;
  // layout: counts@0 (2KB), tok (128KB), wgt (128KB), eslot (32KB),
  //         xb bf16 (4MB), act_r bf16 (11.5MB), act_s bf16 (5.8MB),
  //         outr fp32 (33.5MB).  Total ~55MB (no weight staging anymore).
  int*   counts = (int*)ws;
  int*   tok    = (int*)(ws + 2048);
  float* wgt    = (float*)(ws + 2048 + (size_t)EE * CAP * 4);
  int*   eslot  = (int*)(ws + 2048 + (size_t)EE * CAP * 8);
  short* xb     = (short*)(ws + 2048 + (size_t)EE * CAP * 8 + (size_t)TT * 16);
  short* act_r  = xb + XSZ;                       // [8192][704] bf16
  short* act_s  = act_r + (size_t)8192 * HH;      // [2048][1408] bf16
  float* outr   = (float*)(act_s + (size_t)TT * HSS);  // [8192][1024] fp32

  (void)hipMemsetAsync(counts, 0, EE * CSTR * sizeof(int), stream);

  gate_cvt<<<GATE_BLOCKS + XCVT_BLOCKS, 256, 0, stream>>>(
      x, xb, gate_w, gate_b, counts, tok, wgt, eslot);

  gemm1_merged<<<dim3(11, TT / 128, EE + 2), 512, 0, stream>>>(
      xb, w1, w3, ws1, ws3, act_r, act_s, counts, tok);

  gemm2_merged<<<dim3(DD / 128, TT / 128, EE + 1), 512, 0, stream>>>(
      act_r, act_s, w2, ws2, y, outr, counts, wgt);

  combine_kernel<<<TT, 256, 0, stream>>>(y, outr, eslot, counts);
}

// Round 9
// 331.299 us; speedup vs baseline: 1.0499x; 1.0499x over previous
//
#include <hip/hip_runtime.h>
#include <hip/hip_bf16.h>
#include <math.h>

// ---------------- types ----------------
typedef __attribute__((ext_vector_type(4))) float   f32x4;
typedef __attribute__((ext_vector_type(8))) short   short8;
typedef __attribute__((ext_vector_type(8))) __bf16  bf16x8;

union SB8 { short8 s; bf16x8 b; };

__device__ __forceinline__ short f2bf(float f) {
  union { float f; unsigned u; } v; v.f = f;
  unsigned r = v.u + 0x7fffu + ((v.u >> 16) & 1u);   // RNE
  return (short)(r >> 16);
}

__device__ __forceinline__ short8 cvt8(f32x4 a, f32x4 b) {
  short8 r;
  r[0] = f2bf(a[0]); r[1] = f2bf(a[1]); r[2] = f2bf(a[2]); r[3] = f2bf(a[3]);
  r[4] = f2bf(b[0]); r[5] = f2bf(b[1]); r[6] = f2bf(b[2]); r[7] = f2bf(b[3]);
  return r;
}

// async global->LDS, 16B per lane; dest is wave-uniform base + lane*16
__device__ __forceinline__ void ldsload16(const short* g, short* l) {
  __builtin_amdgcn_global_load_lds(
      (const __attribute__((address_space(1))) unsigned int*)g,
      (__attribute__((address_space(3))) unsigned int*)l, 16, 0, 0);
}

// Problem constants
#define TT   2048
#define DD   1024        // K of gemm1, N of gemm2
#define HH   704
#define HSS  1408
#define EE   16
#define CAP  2048
#define CSTR 32          // counts stride in ints (128B apart)

// bf16 workspace segment offsets (elements): x | w1 | w3 | ws1 | ws3
#define O1  2097152ULL                    // x end
#define O2  13631488ULL                   // w1 end
#define O3  25165824ULL                   // w3 end
#define WS1END 26607616ULL                // ws1 end
#define CVTA_TOTAL 28049408ULL            // ws3 end (= 3424 * 8192)
#define CVTA_BLOCKS 3424
#define GATE_BLOCKS 512

// ---------------- fused gate + fp32->bf16 convert (x + gemm1 weights) --------
// w2/ws2 are NOT converted: gemm2 reg-stages them fp32->bf16 (its routed panel
// 2.88MB fp32 L2-fits; gemm1's 5.77MB does not — r8 lesson).
__global__ __launch_bounds__(256)
void gate_cvt(const float* __restrict__ x,  const float* __restrict__ w1,
              const float* __restrict__ w3, const float* __restrict__ s1,
              const float* __restrict__ s3, short* __restrict__ dst,
              const float* __restrict__ gw, const float* __restrict__ gb,
              int* __restrict__ counts, int* __restrict__ tok,
              float* __restrict__ wgt)
{
  if (blockIdx.x >= GATE_BLOCKS) {
    const int tid = threadIdx.x;
    const size_t base = (size_t)(blockIdx.x - GATE_BLOCKS) * 8192;
    const float* sp[4]; short* dp[4];
    #pragma unroll
    for (int k = 0; k < 4; k++) {
      const size_t sb = base + (size_t)k * 2048;          // uniform per (block,k)
      const float* src;
      if      (sb < O1)     src = x  + sb;
      else if (sb < O2)     src = w1 + (sb - O1);
      else if (sb < O3)     src = w3 + (sb - O2);
      else if (sb < WS1END) src = s1 + (sb - O3);
      else                  src = s3 + (sb - WS1END);
      sp[k] = src + tid * 8;
      dp[k] = dst + sb + tid * 8;
    }
    f32x4 va[8];
    #pragma unroll
    for (int k = 0; k < 4; k++) {
      va[2 * k]     = *(const f32x4*)(sp[k]);
      va[2 * k + 1] = *(const f32x4*)(sp[k] + 4);
    }
    #pragma unroll
    for (int k = 0; k < 4; k++)
      *(short8*)(dp[k]) = cvt8(va[2 * k], va[2 * k + 1]);
    return;
  }

  // ---- gate part ----
  const int lane = threadIdx.x & 63;
  const int wid  = threadIdx.x >> 6;
  const int t    = blockIdx.x * 4 + wid;
  const int e    = lane & 15;
  const int p    = lane >> 4;

  const float* xp = x + (size_t)t * DD + p * 256;
  const float* gp = gw + (size_t)e * DD + p * 256;

  double a0 = 0.0, a1 = 0.0, a2 = 0.0, a3 = 0.0;
  #pragma unroll 8
  for (int i = 0; i < 64; i++) {
    f32x4 xa = *(const f32x4*)(xp + i * 4);
    f32x4 ga = *(const f32x4*)(gp + i * 4);
    a0 += (double)xa[0] * (double)ga[0];
    a1 += (double)xa[1] * (double)ga[1];
    a2 += (double)xa[2] * (double)ga[2];
    a3 += (double)xa[3] * (double)ga[3];
  }
  double acc = (a0 + a1) + (a2 + a3);
  acc += __shfl_xor(acc, 16);
  acc += __shfl_xor(acc, 32);
  float accf = (float)acc;

  float lf[EE], sc[EE], r[EE];
  #pragma unroll
  for (int j = 0; j < EE; j++) lf[j] = __shfl(accf, j);
  #pragma unroll
  for (int j = 0; j < EE; j++) {
    sc[j] = 1.f / (1.f + expf(-lf[j]));
    r[j] = sc[j] + gb[j];
  }
  float gs[4];
  #pragma unroll
  for (int g = 0; g < 4; g++) {
    float m1 = -1e30f, m2 = -1e30f;
    #pragma unroll
    for (int j = 0; j < 4; j++) {
      float v = r[g * 4 + j];
      if (v > m1) { m2 = m1; m1 = v; }
      else if (v > m2) { m2 = v; }
    }
    gs[g] = m1 + m2;
  }
  int g1 = 0, g2 = -1; float b1 = -1e30f, b2 = -1e30f;
  #pragma unroll
  for (int g = 0; g < 4; g++) {
    if (gs[g] > b1) { b2 = b1; g2 = g1; b1 = gs[g]; g1 = g; }
    else if (gs[g] > b2) { b2 = gs[g]; g2 = g; }
  }
  int idx[4]; float wv[4]; float wsum = 0.f;
  unsigned used = 0;
  #pragma unroll
  for (int k = 0; k < 4; k++) {
    float best = -1e30f; int bi = 0;
    #pragma unroll
    for (int j = 0; j < EE; j++) {
      int g = j >> 2;
      bool keep = (g == g1) || (g == g2);
      if (keep && !((used >> j) & 1) && r[j] > best) { best = r[j]; bi = j; }
    }
    used |= 1u << bi; idx[k] = bi; wv[k] = sc[bi]; wsum += sc[bi];
  }
  float div = wsum < 1e-9f ? 1e-9f : wsum;
  if (lane < 4) {
    float w = wv[lane] / div * 2.5446f;
    int slot = atomicAdd(&counts[idx[lane] * CSTR], 1);
    tok[idx[lane] * CAP + slot] = t;
    wgt[idx[lane] * CAP + slot] = w;
  }
}

// counted-vmcnt pipeline (gemm1: 4 gload_lds per stage)
#define WAIT_PREV_TILE()  do { \
    asm volatile("s_waitcnt vmcnt(4)" ::: "memory"); \
    __builtin_amdgcn_sched_barrier(0); \
    __builtin_amdgcn_s_barrier(); \
    __builtin_amdgcn_sched_barrier(0); } while (0)
#define WAIT_LAST_TILE()  do { \
    asm volatile("s_waitcnt vmcnt(0)" ::: "memory"); \
    __builtin_amdgcn_sched_barrier(0); \
    __builtin_amdgcn_s_barrier(); \
    __builtin_amdgcn_sched_barrier(0); } while (0)
#define END_TILE_BARRIER() do { \
    __builtin_amdgcn_sched_barrier(0); \
    __builtin_amdgcn_s_barrier(); } while (0)
// reg-staged pipeline (gemm2)
#define PIPE_VM_WAIT() do { \
    asm volatile("s_waitcnt vmcnt(0)" ::: "memory"); \
    __builtin_amdgcn_sched_barrier(0); \
    __builtin_amdgcn_s_barrier(); \
    __builtin_amdgcn_sched_barrier(0); } while (0)
#define PIPE_LGKM_BAR() do { \
    asm volatile("s_waitcnt lgkmcnt(0)" ::: "memory"); \
    __builtin_amdgcn_sched_barrier(0); \
    __builtin_amdgcn_s_barrier(); \
    __builtin_amdgcn_sched_barrier(0); } while (0)

// ---------------- merged GEMM1 + SwiGLU (bf16, 8-wave dbuf, r6 structure) ------
// grid (11,16,18) = 3168 = 8*396 ranks: [0,352) routed e = r8+8*(rank/176)
// (expert-clustered per XCD, Nt-minor); [352,396) shared (16Mt x 22Nt).
// Tile M=128, N=64 dual, BK=64, dbuf 64KB LDS, counted vmcnt(4).
// NO convert plane anymore (w2/ws2 handled by gemm2 reg-staging).
__global__ __launch_bounds__(512, 2)
void gemm1_merged(const short* __restrict__ xb, const short* __restrict__ w1b,
                  const short* __restrict__ w3b, const short* __restrict__ ws1b,
                  const short* __restrict__ ws3b, short* __restrict__ act_r,
                  short* __restrict__ act_s, const int* __restrict__ counts,
                  const int* __restrict__ tok)
{
  const int F = blockIdx.x + 11 * (blockIdx.y + 16 * blockIdx.z);
  const int r8 = F & 7, rank = F >> 3;
  int z, Mt, Ntc;
  if (rank < 352) {                   // routed, clustered per XCD
    z = r8 + 8 * (rank / 176);
    const int p = rank % 176;
    Mt = p / 11; Ntc = p % 11;        // Nt-minor
  } else {                            // shared FFN, spread across XCDs
    z = 16;
    const int p = (rank - 352) * 8 + r8;
    Mt = p / 22; Ntc = p % 22;
  }

  const bool routed = (z < EE);
  int cnt, N, rowbase = 0;
  const short *W1, *W3;
  short* act;
  if (routed) {
    cnt = counts[z * CSTR];
    if (Mt * 128 >= cnt) return;
    int rb = 0;
    for (int i = 0; i < z; i++) rb += counts[i * CSTR];
    rowbase = rb;
    N = HH;
    W1 = w1b + (size_t)z * HH * DD;
    W3 = w3b + (size_t)z * HH * DD;
    act = act_r;
  } else {
    cnt = TT; N = HSS; W1 = ws1b; W3 = ws3b; act = act_s;
  }
  const int NtB = Ntc * 64;

  __shared__ __align__(16) short lA [2][128 * 64];
  __shared__ __align__(16) short lB1[2][64 * 64];
  __shared__ __align__(16) short lB3[2][64 * 64];

  const int tid = threadIdx.x, lane = tid & 63, wv = tid >> 6;   // wv 0..7
  const int srow = lane >> 3, schunk = lane & 7, scg = schunk ^ srow;

  const short* pa[2];
  #pragma unroll
  for (int i = 0; i < 2; i++) {
    const int g = wv * 2 + i;
    int arow = Mt * 128 + g * 8 + srow;
    if (routed) {
      int slot = arow < cnt ? arow : cnt - 1;
      arow = tok[z * CAP + slot];
    }
    pa[i] = xb + (size_t)arow * DD + scg * 8;
  }
  const short *pb1, *pb3;
  {
    const int brow = NtB + wv * 8 + srow;      // <= N-1 (exact tiling)
    pb1 = W1 + (size_t)brow * DD + scg * 8;
    pb3 = W3 + (size_t)brow * DD + scg * 8;
  }

  f32x4 acc1[4], acc3[4];
  #pragma unroll
  for (int i = 0; i < 4; i++) { acc1[i] = (f32x4)0.f; acc3[i] = (f32x4)0.f; }

  const int q = lane >> 4, r7 = lane & 7, hi = (lane & 15) >> 3;
  const int wc = wv & 3, mh = wv >> 2;

#define STAGE1(c, kk) do { \
    ldsload16(pa[0] + (kk), &lA [c][(wv * 2 + 0) * 512]); \
    ldsload16(pa[1] + (kk), &lA [c][(wv * 2 + 1) * 512]); \
    ldsload16(pb1  + (kk),  &lB1[c][wv * 512]); \
    ldsload16(pb3  + (kk),  &lB3[c][wv * 512]); } while (0)

#define GEMM1_BODY(c) do { \
    _Pragma("unroll") for (int kc = 0; kc < 2; kc++) { \
      const int cx = (kc * 4 + q) ^ r7; \
      SB8 b1f, b3f; \
      b1f.s = *(const short8*)(&lB1[c][((wc * 2 + hi) * 64 + r7 * 8 + cx) * 8]); \
      b3f.s = *(const short8*)(&lB3[c][((wc * 2 + hi) * 64 + r7 * 8 + cx) * 8]); \
      _Pragma("unroll") for (int mt = 0; mt < 4; mt++) { \
        SB8 af; af.s = *(const short8*)(&lA[c][((2 * (mh * 4 + mt) + hi) * 64 + r7 * 8 + cx) * 8]); \
        acc1[mt] = __builtin_amdgcn_mfma_f32_16x16x32_bf16(af.b, b1f.b, acc1[mt], 0, 0, 0); \
        acc3[mt] = __builtin_amdgcn_mfma_f32_16x16x32_bf16(af.b, b3f.b, acc3[mt], 0, 0, 0); \
      } } } while (0)

  STAGE1(0, 0);
  int cur = 0;
  for (int kk = 64; kk < DD; kk += 64) {
    STAGE1(cur ^ 1, kk);
    WAIT_PREV_TILE();
    GEMM1_BODY(cur);
    END_TILE_BARRIER();
    cur ^= 1;
  }
  WAIT_LAST_TILE();
  GEMM1_BODY(cur);

  const int quad = lane >> 4, lcol = lane & 15;
  const int col = NtB + wc * 16 + lcol;
  #pragma unroll
  for (int mt = 0; mt < 4; mt++) {
    #pragma unroll
    for (int rg = 0; rg < 4; rg++) {
      const int r = Mt * 128 + (mh * 4 + mt) * 16 + quad * 4 + rg;
      if (r < cnt) {
        float g = acc1[mt][rg], u = acc3[mt][rg];
        float a = g / (1.f + __expf(-g)) * u;
        act[(size_t)(rowbase + r) * N + col] = f2bf(a);
      }
    }
  }
#undef STAGE1
#undef GEMM1_BODY
}

// ---------------- merged GEMM2 (down proj, fp32-B reg-staged, atomic-y) --------
// grid (8,16,17) = 2176, 512 threads, tile 128x128, BK=64, dbuf 64KB LDS.
// B = w2/ws2 fp32 -> cvt8 -> ds_write (routed panel 2.88MB fp32 L2-fits).
// Epilogue: atomicAdd directly into y (pre-zeroed) — combine kernel + outr
// round-trip eliminated.  Routed rows map slot->token via tok[].
__global__ __launch_bounds__(512, 2)
void gemm2_merged(const short* __restrict__ act_r, const short* __restrict__ act_s,
                  const float* __restrict__ w2f, const float* __restrict__ ws2f,
                  float* __restrict__ y,
                  const int* __restrict__ counts, const float* __restrict__ wgt,
                  const int* __restrict__ tok)
{
  const int F = blockIdx.x + 8 * (blockIdx.y + 16 * blockIdx.z);
  const int r8 = F & 7, rank = F >> 3;
  int z, Mt, Nt;
  if (rank < 256) {
    z = r8 + 8 * (rank >> 7);
    const int p = rank & 127;
    Mt = p >> 3; Nt = p & 7;
  } else {
    z = 16;
    const int p = (rank - 256) * 8 + r8;
    Mt = p >> 3; Nt = p & 7;
  }

  const bool routed = (z < EE);

  int cnt, Kd, rowbase = 0;
  const short* A;
  const float* W;
  if (routed) {
    cnt = counts[z * CSTR];
    if (Mt * 128 >= cnt) return;
    int rb = 0;
    for (int i = 0; i < z; i++) rb += counts[i * CSTR];
    rowbase = rb;
    Kd = HH;
    A = act_r + (size_t)rowbase * HH;
    W = w2f + (size_t)z * DD * HH;
  } else {
    cnt = TT; Kd = HSS; A = act_s; W = ws2f;
  }

  __shared__ __align__(16) short lA[2][128 * 64];
  __shared__ __align__(16) short lB[2][128 * 64];

  const int tid = threadIdx.x, lane = tid & 63, wv = tid >> 6;   // wv 0..7
  const int srow = lane >> 3, schunk = lane & 7, scg = schunk ^ srow;

  const short* pa[2]; const float* pbf[2];
  #pragma unroll
  for (int i = 0; i < 2; i++) {
    const int g = wv * 2 + i;
    int arow = Mt * 128 + g * 8 + srow;
    if (arow >= cnt) arow = cnt - 1;
    pa[i] = A + (size_t)arow * Kd + scg * 8;
    const int brow = Nt * 128 + g * 8 + srow;   // <= 1023 always
    pbf[i] = W + (size_t)brow * Kd + scg * 8;
  }

  f32x4 acc[4][2];
  #pragma unroll
  for (int i = 0; i < 4; i++) { acc[i][0] = (f32x4)0.f; acc[i][1] = (f32x4)0.f; }
  f32x4 rbw[4];

  const int q = lane >> 4, r7 = lane & 7, hi = (lane & 15) >> 3;
  const int wc = wv & 3, mh = wv >> 2;
  const int wofs0 = (wv * 2 + 0) * 512 + srow * 64 + schunk * 8;
  const int wofs1 = (wv * 2 + 1) * 512 + srow * 64 + schunk * 8;

#define STAGE2_ISSUE(c, kk) do { \
    ldsload16(pa[0] + (kk), &lA[c][(wv * 2 + 0) * 512]); \
    ldsload16(pa[1] + (kk), &lA[c][(wv * 2 + 1) * 512]); \
    rbw[0] = *(const f32x4*)(pbf[0] + (kk)); \
    rbw[1] = *(const f32x4*)(pbf[0] + (kk) + 4); \
    rbw[2] = *(const f32x4*)(pbf[1] + (kk)); \
    rbw[3] = *(const f32x4*)(pbf[1] + (kk) + 4); } while (0)

#define STAGE2_WRITE(c) do { \
    *(short8*)(&lB[c][wofs0]) = cvt8(rbw[0], rbw[1]); \
    *(short8*)(&lB[c][wofs1]) = cvt8(rbw[2], rbw[3]); } while (0)

#define GEMM2_BODY(c) do { \
    _Pragma("unroll") for (int kc = 0; kc < 2; kc++) { \
      const int cx = (kc * 4 + q) ^ r7; \
      SB8 bf[2]; \
      _Pragma("unroll") for (int ntl = 0; ntl < 2; ntl++) { \
        const int a16 = ((wc * 2 + ntl) * 2 + hi) * 64 + r7 * 8 + cx; \
        bf[ntl].s = *(const short8*)(&lB[c][a16 * 8]); \
      } \
      _Pragma("unroll") for (int mt = 0; mt < 4; mt++) { \
        const int a16 = (2 * (mh * 4 + mt) + hi) * 64 + r7 * 8 + cx; \
        SB8 af; af.s = *(const short8*)(&lA[c][a16 * 8]); \
        acc[mt][0] = __builtin_amdgcn_mfma_f32_16x16x32_bf16(af.b, bf[0].b, acc[mt][0], 0, 0, 0); \
        acc[mt][1] = __builtin_amdgcn_mfma_f32_16x16x32_bf16(af.b, bf[1].b, acc[mt][1], 0, 0, 0); \
      } } } while (0)

  STAGE2_ISSUE(0, 0);
  asm volatile("s_waitcnt vmcnt(0)" ::: "memory");
  __builtin_amdgcn_sched_barrier(0);
  STAGE2_WRITE(0);
  PIPE_LGKM_BAR();
  int cur = 0;
  for (int kk = 64; kk < Kd; kk += 64) {
    STAGE2_ISSUE(cur ^ 1, kk);
    GEMM2_BODY(cur);
    PIPE_VM_WAIT();
    STAGE2_WRITE(cur ^ 1);
    PIPE_LGKM_BAR();
    cur ^= 1;
  }
  GEMM2_BODY(cur);

  const int quad = lane >> 4, lcol = lane & 15;
  #pragma unroll
  for (int mt = 0; mt < 4; mt++) {
    #pragma unroll
    for (int ntl = 0; ntl < 2; ntl++) {
      const int col = Nt * 128 + (wc * 2 + ntl) * 16 + lcol;
      #pragma unroll
      for (int rg = 0; rg < 4; rg++) {
        const int slot = Mt * 128 + (mh * 4 + mt) * 16 + quad * 4 + rg;
        const float v = acc[mt][ntl][rg];
        if (routed) {
          if (slot < cnt) {
            const float w = wgt[z * CAP + slot];
            const int t = tok[z * CAP + slot];
            atomicAdd(&y[(size_t)t * DD + col], w * v);
          }
        } else {
          atomicAdd(&y[(size_t)slot * DD + col], v);
        }
      }
    }
  }
#undef STAGE2_ISSUE
#undef STAGE2_WRITE
#undef GEMM2_BODY
}

// ---------------- launch ----------------
extern "C" void kernel_launch(void* const* d_in, const int* in_sizes, int n_in,
                              void* d_out, int out_size, void* d_ws, size_t ws_size,
                              hipStream_t stream) {
  const float* x      = (const float*)d_in[0];
  const float* gate_w = (const float*)d_in[1];
  const float* gate_b = (const float*)d_in[2];
  const float* w1     = (const float*)d_in[3];
  const float* w3     = (const float*)d_in[4];
  const float* w2     = (const float*)d_in[5];
  const float* ws1    = (const float*)d_in[6];
  const float* ws3    = (const float*)d_in[7];
  const float* ws2    = (const float*)d_in[8];
  float* y = (float*)d_out;

  char* ws = (char*)d_ws;
  // layout: counts@0 (2KB), tok (128KB), wgt (128KB),
  //         bf16 area x|w1|w3|ws1|ws3 (56MB), act_r (11.5MB), act_s (5.8MB).
  int*   counts = (int*)ws;
  int*   tok    = (int*)(ws + 2048);
  float* wgt    = (float*)(ws + 2048 + (size_t)EE * CAP * 4);
  short* bf     = (short*)(ws + 2048 + (size_t)EE * CAP * 8);
  short* xb   = bf;
  short* w1b  = bf + O1;
  short* w3b  = bf + O2;
  short* ws1b = bf + O3;
  short* ws3b = bf + WS1END;
  short* act_r = bf + CVTA_TOTAL;                // [8192][704] bf16
  short* act_s = act_r + (size_t)8192 * HH;      // [2048][1408] bf16

  (void)hipMemsetAsync(counts, 0, EE * CSTR * sizeof(int), stream);
  (void)hipMemsetAsync(y, 0, (size_t)TT * DD * sizeof(float), stream);

  gate_cvt<<<GATE_BLOCKS + CVTA_BLOCKS, 256, 0, stream>>>(
      x, w1, w3, ws1, ws3, bf,
      gate_w, gate_b, counts, tok, wgt);

  gemm1_merged<<<dim3(11, TT / 128, EE + 2), 512, 0, stream>>>(
      xb, w1b, w3b, ws1b, ws3b, act_r, act_s, counts, tok);

  gemm2_merged<<<dim3(DD / 128, TT / 128, EE + 1), 512, 0, stream>>>(
      act_r, act_s, w2, ws2, y, counts, wgt, tok);
}